// Round 3
// baseline (357.423 us; speedup 1.0000x reference)
//
#include <hip/hip_runtime.h>
#include <hip/hip_cooperative_groups.h>

namespace cg = cooperative_groups;

typedef unsigned int u32;
typedef unsigned short u16;
typedef unsigned long long u64;

#define NTOK 4096
#define DDIM 512
#define NEXP 8
#define HDIM 1024

#define XN   ((size_t)NTOK * DDIM)            // 2,097,152
#define W1N  ((size_t)NEXP * 2 * HDIM * DDIM) // 8,388,608
#define B1N  ((size_t)NEXP * 2 * HDIM)        // 16,384
#define W2N  ((size_t)NEXP * DDIM * HDIM)     // 4,194,304
#define B2N  ((size_t)NEXP * DDIM)            // 4,096

typedef __attribute__((ext_vector_type(8))) __bf16 bf16x8;
typedef __attribute__((ext_vector_type(4))) float f32x4;

typedef const void __attribute__((address_space(1))) as1_cvoid;
typedef void __attribute__((address_space(3))) as3_void;

__device__ __forceinline__ float b2f(u16 u) {
    union { u32 i; float f; } v; v.i = ((u32)u) << 16; return v.f;
}
__device__ __forceinline__ u16 f2b(float f) {
    u32 x = __builtin_bit_cast(u32, f);
    x += 0x7fffu + ((x >> 16) & 1u);
    return (u16)(x >> 16);
}

// width-16 direct global->LDS. LDS dest is wave-uniform base + lane*16
// (linear); swizzle lives in the per-lane GLOBAL source address (rule 21).
__device__ __forceinline__ void gl16(const u16* g, u16* l) {
    __builtin_amdgcn_global_load_lds((as1_cvoid*)g, (as3_void*)l, 16, 0, 0);
}

__device__ __forceinline__ void convert8(const float* __restrict__ src,
                                         u16* __restrict__ dst, size_t off) {
    const float4 a = *(const float4*)(src + off);
    const float4 b = *(const float4*)(src + off + 4);
    union { u16 t[8]; uint4 v; } u;
    u.t[0] = f2b(a.x); u.t[1] = f2b(a.y); u.t[2] = f2b(a.z); u.t[3] = f2b(a.w);
    u.t[4] = f2b(b.x); u.t[5] = f2b(b.y); u.t[6] = f2b(b.z); u.t[7] = f2b(b.w);
    *(uint4*)(dst + off) = u.v;
}

// ---- router for one token (one wave). Verified numerics (rounds 0-2). ----
__device__ __forceinline__ void router_one(
    const float* __restrict__ x, const float* __restrict__ rw, const float* __restrict__ rb,
    u16* __restrict__ tok_epack, float* __restrict__ tok_w, int t, int lane)
{
    const float4* p = (const float4*)(x + (size_t)t * DDIM + lane * 8);
    const float4 xa = p[0], xc = p[1];
    float xf[8] = { xa.x, xa.y, xa.z, xa.w, xc.x, xc.y, xc.z, xc.w };

    float acc[NEXP];
#pragma unroll
    for (int e = 0; e < NEXP; e++) {
        const float4* q = (const float4*)(rw + e * DDIM + lane * 8);
        const float4 wa = q[0], wb = q[1];
        acc[e] = xf[0] * wa.x + xf[1] * wa.y + xf[2] * wa.z + xf[3] * wa.w
               + xf[4] * wb.x + xf[5] * wb.y + xf[6] * wb.z + xf[7] * wb.w;
    }
#pragma unroll
    for (int off = 32; off > 0; off >>= 1) {
#pragma unroll
        for (int e = 0; e < NEXP; e++) acc[e] += __shfl_xor(acc[e], off, 64);
    }
    if (lane == 0) {
#pragma unroll
        for (int e = 0; e < NEXP; e++) acc[e] += rb[e];
        int e0 = 0;
#pragma unroll
        for (int e = 1; e < NEXP; e++) if (acc[e] > acc[e0]) e0 = e;
        int e1 = -1;
#pragma unroll
        for (int e = 0; e < NEXP; e++) {
            if (e == e0) continue;
            if (e1 < 0 || acc[e] > acc[e1]) e1 = e;
        }
        const float w1v = 1.f / (1.f + __expf(acc[e0] - acc[e1]));
        tok_epack[t] = (u16)((u32)e0 | ((u32)e1 << 8));
        tok_w[t * 2] = 1.f - w1v;
        tok_w[t * 2 + 1] = w1v;
    }
}

// ---- deterministic ballot compaction, 256 threads (4 waves x 2 experts) ----
__device__ __forceinline__ void build_lists_256(
    const u16* __restrict__ tok_epack,
    u32* __restrict__ counts, u32* __restrict__ offsets,
    u16* __restrict__ list, u32* __restrict__ tok_pos,
    u32* eLDS, int tid)
{
    u32* cLDS = eLDS + NTOK / 2;
    for (int i = tid; i < NTOK / 2; i += 256) eLDS[i] = ((const u32*)tok_epack)[i];
    __syncthreads();
    const int wave = tid >> 6, lane = tid & 63;
    const u64 ltmask = ((u64)1 << lane) - 1;
#pragma unroll
    for (int pass = 0; pass < 2; pass++) {
        const u32 e = (u32)(wave + pass * 4);
        u32 r = 0;
        for (int c = 0; c < 64; c++) {
            const int t = c * 64 + lane;
            const u32 pair = eLDS[t >> 1];
            const u32 p = (pair >> ((t & 1) * 16)) & 0xFFFFu;
            const u32 e0 = p & 0xFFu, e1v = (p >> 8) & 0xFFu;
            const u64 m0 = __ballot(e0 == e);
            if (e0 == e) {
                const u32 idx = r + (u32)__popcll(m0 & ltmask);
                list[e * NTOK + idx] = (u16)t;
                tok_pos[t * 2] = idx;
            }
            r += (u32)__popcll(m0);
            const u64 m1 = __ballot(e1v == e);
            if (e1v == e) {
                const u32 idx = r + (u32)__popcll(m1 & ltmask);
                list[e * NTOK + idx] = (u16)t;
                tok_pos[t * 2 + 1] = idx;
            }
            r += (u32)__popcll(m1);
        }
        if (lane == 0) cLDS[e] = r;
    }
    __syncthreads();
    if (tid == 0) {
        u32 o = 0;
        for (int i = 0; i < NEXP; i++) { counts[i] = cLDS[i]; offsets[i] = o; o += cLDS[i]; }
    }
}

// ---- fc1 + SwiGLU tile: 128 rows x (64 h1 + 64 h2), K=512. Round-2 body. ----
__device__ __forceinline__ void fc1_tile(
    const u16* __restrict__ xb, const u16* __restrict__ w1b, const u16* __restrict__ b1b,
    const u16* __restrict__ list, u16* __restrict__ a_packed,
    int e, int row0, int n0, int cnt, u32 obase,
    u16* As, u16* B1s, u16* B2s, int tid)
{
    const int wave = tid >> 6, lane = tid & 63;
    const int mrow0 = (wave >> 1) * 64;
    const int ncol0 = (wave & 1) * 32;
    const int mm = lane & 15;
    const int qb = lane >> 4;
    const int msw = mm & 7;

    const u16 *srcA[4], *srcB1[2], *srcB2[2];
    u16 *dstA[4], *dstB1[2], *dstB2[2];
    const int lrow8 = lane >> 3;
    const int colOff = ((lane & 7) ^ lrow8) << 3;
#pragma unroll
    for (int j = 0; j < 4; j++) {
        int r = row0 + wave * 32 + j * 8 + lrow8;
        if (r >= cnt) r = cnt - 1;
        const int tok = min((int)list[e * NTOK + r], NTOK - 1);
        srcA[j] = xb + (size_t)tok * DDIM + colOff;
        dstA[j] = &As[(wave * 32 + j * 8) * 64];
    }
#pragma unroll
    for (int j = 0; j < 2; j++) {
        const int n = n0 + wave * 16 + j * 8 + lrow8;
        srcB1[j] = w1b + ((size_t)e * 2 * HDIM + n) * DDIM + colOff;
        srcB2[j] = w1b + ((size_t)e * 2 * HDIM + HDIM + n) * DDIM + colOff;
        dstB1[j] = &B1s[(wave * 16 + j * 8) * 64];
        dstB2[j] = &B2s[(wave * 16 + j * 8) * 64];
    }

    f32x4 acc1[4][2], acc2[4][2];
#pragma unroll
    for (int mt = 0; mt < 4; mt++)
#pragma unroll
        for (int nt = 0; nt < 2; nt++) {
            acc1[mt][nt] = f32x4{0, 0, 0, 0};
            acc2[mt][nt] = f32x4{0, 0, 0, 0};
        }

    for (int k0 = 0; k0 < DDIM; k0 += 64) {
        __syncthreads();
#pragma unroll
        for (int j = 0; j < 4; j++) gl16(srcA[j] + k0, dstA[j]);
#pragma unroll
        for (int j = 0; j < 2; j++) gl16(srcB1[j] + k0, dstB1[j]);
#pragma unroll
        for (int j = 0; j < 2; j++) gl16(srcB2[j] + k0, dstB2[j]);
        __syncthreads();   // compiler drains vmcnt(0) before s_barrier
#pragma unroll
        for (int kk = 0; kk < 2; kk++) {
            const int g = kk * 4 + qb;
            bf16x8 af[4];
#pragma unroll
            for (int mt = 0; mt < 4; mt++)
                af[mt] = *(const bf16x8*)(&As[(mrow0 + mt * 16 + mm) * 64 + ((g ^ msw) << 3)]);
#pragma unroll
            for (int nt = 0; nt < 2; nt++) {
                const bf16x8 b1f = *(const bf16x8*)(&B1s[(ncol0 + nt * 16 + mm) * 64 + ((g ^ msw) << 3)]);
                const bf16x8 b2f = *(const bf16x8*)(&B2s[(ncol0 + nt * 16 + mm) * 64 + ((g ^ msw) << 3)]);
#pragma unroll
                for (int mt = 0; mt < 4; mt++) {
                    acc1[mt][nt] = __builtin_amdgcn_mfma_f32_16x16x32_bf16(af[mt], b1f, acc1[mt][nt], 0, 0, 0);
                    acc2[mt][nt] = __builtin_amdgcn_mfma_f32_16x16x32_bf16(af[mt], b2f, acc2[mt][nt], 0, 0, 0);
                }
            }
        }
    }

    const int rbv = qb * 4;
#pragma unroll
    for (int nt = 0; nt < 2; nt++) {
        const int n = n0 + ncol0 + nt * 16 + mm;
        const float bb1 = b2f(b1b[(size_t)e * 2 * HDIM + n]);
        const float bb2 = b2f(b1b[(size_t)e * 2 * HDIM + HDIM + n]);
#pragma unroll
        for (int mt = 0; mt < 4; mt++) {
#pragma unroll
            for (int r = 0; r < 4; r++) {
                const int gr = row0 + mrow0 + mt * 16 + rbv + r;
                if (gr < cnt) {
                    const float h1 = acc1[mt][nt][r] + bb1;
                    const float h2 = acc2[mt][nt][r] + bb2;
                    const float av = h1 / (1.f + __expf(-h1)) * h2;
                    a_packed[(size_t)(obase + (u32)gr) * HDIM + n] = f2b(av);
                }
            }
        }
    }
}

// ---- fc2 tile: 128 rows x 64 d-cols, K=1024. Round-2 body. ----
__device__ __forceinline__ void fc2_tile(
    const u16* __restrict__ a_packed, const u16* __restrict__ w2b, const u16* __restrict__ b2b,
    u16* __restrict__ y_packed,
    int e, int row0, int d0, int cnt, u32 obase,
    u16* As, u16* Bs, int tid)
{
    const int wave = tid >> 6, lane = tid & 63;
    const int mrow0 = (wave >> 1) * 64;
    const int ncol0 = (wave & 1) * 32;
    const int mm = lane & 15;
    const int qb = lane >> 4;
    const int msw = mm & 7;

    const u16 *srcA[4], *srcB[2];
    u16 *dstA[4], *dstB[2];
    const int lrow8 = lane >> 3;
    const int colOff = ((lane & 7) ^ lrow8) << 3;
#pragma unroll
    for (int j = 0; j < 4; j++) {
        int r = row0 + wave * 32 + j * 8 + lrow8;
        if (r >= cnt) r = cnt - 1;
        srcA[j] = a_packed + (size_t)(obase + (u32)r) * HDIM + colOff;
        dstA[j] = &As[(wave * 32 + j * 8) * 64];
    }
#pragma unroll
    for (int j = 0; j < 2; j++) {
        const int d = d0 + wave * 16 + j * 8 + lrow8;
        srcB[j] = w2b + ((size_t)e * DDIM + d) * HDIM + colOff;
        dstB[j] = &Bs[(wave * 16 + j * 8) * 64];
    }

    f32x4 acc[4][2];
#pragma unroll
    for (int mt = 0; mt < 4; mt++)
#pragma unroll
        for (int nt = 0; nt < 2; nt++) acc[mt][nt] = f32x4{0, 0, 0, 0};

    for (int k0 = 0; k0 < HDIM; k0 += 64) {
        __syncthreads();
#pragma unroll
        for (int j = 0; j < 4; j++) gl16(srcA[j] + k0, dstA[j]);
#pragma unroll
        for (int j = 0; j < 2; j++) gl16(srcB[j] + k0, dstB[j]);
        __syncthreads();
#pragma unroll
        for (int kk = 0; kk < 2; kk++) {
            const int g = kk * 4 + qb;
            bf16x8 af[4];
#pragma unroll
            for (int mt = 0; mt < 4; mt++)
                af[mt] = *(const bf16x8*)(&As[(mrow0 + mt * 16 + mm) * 64 + ((g ^ msw) << 3)]);
#pragma unroll
            for (int nt = 0; nt < 2; nt++) {
                const bf16x8 bfv = *(const bf16x8*)(&Bs[(ncol0 + nt * 16 + mm) * 64 + ((g ^ msw) << 3)]);
#pragma unroll
                for (int mt = 0; mt < 4; mt++)
                    acc[mt][nt] = __builtin_amdgcn_mfma_f32_16x16x32_bf16(af[mt], bfv, acc[mt][nt], 0, 0, 0);
            }
        }
    }

    const int rbv = qb * 4;
#pragma unroll
    for (int nt = 0; nt < 2; nt++) {
        const int n = d0 + ncol0 + nt * 16 + mm;
        const float bb = b2f(b2b[(size_t)e * DDIM + n]);
#pragma unroll
        for (int mt = 0; mt < 4; mt++) {
#pragma unroll
            for (int r = 0; r < 4; r++) {
                const int gr = row0 + mrow0 + mt * 16 + rbv + r;
                if (gr < cnt) {
                    y_packed[(size_t)(obase + (u32)gr) * DDIM + n] = f2b(acc[mt][nt][r] + bb);
                }
            }
        }
    }
}

// =====================================================================
// Mega-kernel. PHASE < 0: cooperative, all phases with grid.sync().
// PHASE = 0..4: standalone phase kernel (fallback, non-cooperative).
// Round-2 post-mortem: 7 serial launches cost ~100us in gaps/bubbles;
// this collapses them into 1 cooperative dispatch (4 grid syncs).
// =====================================================================
template<int PHASE>
__global__ __launch_bounds__(256, 3) void moe_mega(
    const float* __restrict__ x, const float* __restrict__ rw, const float* __restrict__ rb,
    const float* __restrict__ w1, const float* __restrict__ b1,
    const float* __restrict__ w2, const float* __restrict__ b2,
    u16* __restrict__ xb, u16* __restrict__ w1b, u16* __restrict__ b1b,
    u16* __restrict__ w2b, u16* __restrict__ b2b,
    u16* __restrict__ tok_epack, float* __restrict__ tok_w,
    u32* __restrict__ counts, u32* __restrict__ offsets,
    u16* __restrict__ list, u32* __restrict__ tok_pos,
    u16* __restrict__ a_packed, u16* __restrict__ y_packed,
    float* __restrict__ out, int G)
{
    __shared__ alignas(16) u16 SM[16384];   // 32 KB, re-used per phase
    const int tid = threadIdx.x;
    const int bid = (int)blockIdx.x;

    // ---- Phase A: convert x + fc1_w + fc1_b, and router ----
    if constexpr (PHASE < 0 || PHASE == 0) {
        const size_t nIt = (XN + W1N + B1N) / 8;
        for (size_t it = (size_t)bid * 256 + tid; it < nIt; it += (size_t)G * 256) {
            const size_t i = it * 8;
            const float* src; u16* dst; size_t off;
            if (i < XN)            { src = x;  dst = xb;  off = i; }
            else if (i < XN + W1N) { src = w1; dst = w1b; off = i - XN; }
            else                   { src = b1; dst = b1b; off = i - XN - W1N; }
            convert8(src, dst, off);
        }
        const int nW = G * 4;
        for (int t = bid * 4 + (tid >> 6); t < NTOK; t += nW)
            router_one(x, rw, rb, tok_epack, tok_w, t, tid & 63);
    }
    if constexpr (PHASE < 0) cg::this_grid().sync();

    // ---- Phase B: block 0 builds lists; others convert fc2_w + fc2_b ----
    if constexpr (PHASE < 0 || PHASE == 1) {
        if (bid == 0) {
            build_lists_256(tok_epack, counts, offsets, list, tok_pos, (u32*)SM, tid);
        } else {
            const size_t nIt = (W2N + B2N) / 8;
            for (size_t it = (size_t)(bid - 1) * 256 + tid; it < nIt; it += (size_t)(G - 1) * 256) {
                const size_t i = it * 8;
                const float* src; u16* dst; size_t off;
                if (i < W2N) { src = w2; dst = w2b; off = i; }
                else         { src = b2; dst = b2b; off = i - W2N; }
                convert8(src, dst, off);
            }
        }
    }
    if constexpr (PHASE < 0) cg::this_grid().sync();

    // ---- Phase C: fc1 + SwiGLU over active tiles (grid-stride) ----
    if constexpr (PHASE < 0 || PHASE == 2) {
        u32 cnts[NEXP], offs[NEXP];
        u32 tot = 0;
#pragma unroll
        for (int e = 0; e < NEXP; e++) {
            cnts[e] = counts[e]; offs[e] = offsets[e];
            tot += ((cnts[e] + 127) >> 7) * (HDIM / 64);
        }
        for (u32 tile = (u32)bid; tile < tot; tile += (u32)G) {
            u32 rem = tile; int e = 0; u32 loc = 0; int found = 0;
#pragma unroll
            for (int q = 0; q < NEXP; q++) {
                const u32 sz = ((cnts[q] + 127) >> 7) * (HDIM / 64);
                if (!found) {
                    if (rem < sz) { e = q; loc = rem; found = 1; }
                    else rem -= sz;
                }
            }
            const int row0 = (int)(loc / (HDIM / 64)) * 128;
            const int n0   = (int)(loc % (HDIM / 64)) * 64;
            fc1_tile(xb, w1b, b1b, list, a_packed, e, row0, n0,
                     (int)cnts[e], offs[e], SM, SM + 8192, SM + 12288, tid);
        }
    }
    if constexpr (PHASE < 0) cg::this_grid().sync();

    // ---- Phase D: fc2 over active tiles (grid-stride) ----
    if constexpr (PHASE < 0 || PHASE == 3) {
        u32 cnts[NEXP], offs[NEXP];
        u32 tot = 0;
#pragma unroll
        for (int e = 0; e < NEXP; e++) {
            cnts[e] = counts[e]; offs[e] = offsets[e];
            tot += ((cnts[e] + 127) >> 7) * (DDIM / 64);
        }
        for (u32 tile = (u32)bid; tile < tot; tile += (u32)G) {
            u32 rem = tile; int e = 0; u32 loc = 0; int found = 0;
#pragma unroll
            for (int q = 0; q < NEXP; q++) {
                const u32 sz = ((cnts[q] + 127) >> 7) * (DDIM / 64);
                if (!found) {
                    if (rem < sz) { e = q; loc = rem; found = 1; }
                    else rem -= sz;
                }
            }
            const int row0 = (int)(loc / (DDIM / 64)) * 128;
            const int d0   = (int)(loc % (DDIM / 64)) * 64;
            fc2_tile(a_packed, w2b, b2b, y_packed, e, row0, d0,
                     (int)cnts[e], offs[e], SM, SM + 8192, tid);
        }
    }
    if constexpr (PHASE < 0) cg::this_grid().sync();

    // ---- Phase E: weighted combine (one wave per token, f32 out) ----
    if constexpr (PHASE < 0 || PHASE == 4) {
        const int lane = tid & 63;
        const int nW = G * 4;
        for (int t = bid * 4 + (tid >> 6); t < NTOK; t += nW) {
            const u32 pk = (u32)tok_epack[t];
            const u32 e0 = pk & 7u, e1 = (pk >> 8) & 7u;
            const u32 p0 = min(offsets[e0] + tok_pos[t * 2],     (u32)(2 * NTOK - 1));
            const u32 p1 = min(offsets[e1] + tok_pos[t * 2 + 1], (u32)(2 * NTOK - 1));
            const float w0 = tok_w[t * 2], w1w = tok_w[t * 2 + 1];
            const uint4 va = *(const uint4*)(y_packed + (size_t)p0 * DDIM + lane * 8);
            const uint4 vb = *(const uint4*)(y_packed + (size_t)p1 * DDIM + lane * 8);
            const u16* ap = (const u16*)&va;
            const u16* bp = (const u16*)&vb;
            float r[8];
#pragma unroll
            for (int j = 0; j < 8; j++) r[j] = w0 * b2f(ap[j]) + w1w * b2f(bp[j]);
            float* op = out + (size_t)t * DDIM + lane * 8;
            *(float4*)op       = float4{r[0], r[1], r[2], r[3]};
            *(float4*)(op + 4) = float4{r[4], r[5], r[6], r[7]};
        }
    }
}

extern "C" void kernel_launch(void* const* d_in, const int* in_sizes, int n_in,
                              void* d_out, int out_size, void* d_ws, size_t ws_size,
                              hipStream_t stream)
{
    const float* x  = (const float*)d_in[0];
    const float* rw = (const float*)d_in[1];
    const float* rb = (const float*)d_in[2];
    const float* w1 = (const float*)d_in[3];
    const float* b1 = (const float*)d_in[4];
    const float* w2 = (const float*)d_in[5];
    const float* b2 = (const float*)d_in[6];
    float* outp = (float*)d_out;
    (void)in_sizes; (void)n_in; (void)out_size; (void)ws_size;

    char* ws = (char*)d_ws;
    size_t off = 0;
    auto take = [&](size_t bytes) -> char* {
        char* p = ws + off;
        off = (off + bytes + 255) & ~(size_t)255;
        return p;
    };
    u32* counts    = (u32*)take(NEXP * 4);
    u32* offsets   = (u32*)take(NEXP * 4);
    u16* list      = (u16*)take((size_t)NEXP * NTOK * 2);
    u16* tok_epack = (u16*)take((size_t)NTOK * 2);
    u32* tok_pos   = (u32*)take((size_t)NTOK * 2 * 4);
    float* tok_w   = (float*)take((size_t)NTOK * 2 * 4);
    u16* a_packed  = (u16*)take((size_t)2 * NTOK * HDIM * 2);   // 33.6 MB
    u16* y_packed  = (u16*)take((size_t)2 * NTOK * DDIM * 2);   // 16.8 MB
    u16* xb  = (u16*)take(XN * 2);
    u16* w1b = (u16*)take(W1N * 2);
    u16* b1b = (u16*)take(B1N * 2);
    u16* w2b = (u16*)take(W2N * 2);
    u16* b2b = (u16*)take(B2N * 2);

    // co-residency clamp for cooperative launch (host-side query, capture-safe)
    auto kfn = moe_mega<-1>;
    int maxB = 0;
    int G = 256;
    if (hipOccupancyMaxActiveBlocksPerMultiprocessor(&maxB, kfn, 256, 0) == hipSuccess && maxB > 0) {
        G = maxB * 256;               // 256 CUs on MI355X
        if (G > 768) G = 768;
    }

    void* args[] = {
        (void*)&x, (void*)&rw, (void*)&rb, (void*)&w1, (void*)&b1,
        (void*)&w2, (void*)&b2,
        (void*)&xb, (void*)&w1b, (void*)&b1b, (void*)&w2b, (void*)&b2b,
        (void*)&tok_epack, (void*)&tok_w,
        (void*)&counts, (void*)&offsets, (void*)&list, (void*)&tok_pos,
        (void*)&a_packed, (void*)&y_packed, (void*)&outp, (void*)&G
    };

    hipError_t cerr = hipLaunchCooperativeKernel(kfn, dim3((u32)G), dim3(256),
                                                 args, 0, stream);
    if (cerr != hipSuccess) {
        // fallback: same template as 5 serial phase kernels
        const int GF = 768;
        moe_mega<0><<<GF, 256, 0, stream>>>(x, rw, rb, w1, b1, w2, b2,
            xb, w1b, b1b, w2b, b2b, tok_epack, tok_w,
            counts, offsets, list, tok_pos, a_packed, y_packed, outp, GF);
        moe_mega<1><<<GF, 256, 0, stream>>>(x, rw, rb, w1, b1, w2, b2,
            xb, w1b, b1b, w2b, b2b, tok_epack, tok_w,
            counts, offsets, list, tok_pos, a_packed, y_packed, outp, GF);
        moe_mega<2><<<GF, 256, 0, stream>>>(x, rw, rb, w1, b1, w2, b2,
            xb, w1b, b1b, w2b, b2b, tok_epack, tok_w,
            counts, offsets, list, tok_pos, a_packed, y_packed, outp, GF);
        moe_mega<3><<<GF, 256, 0, stream>>>(x, rw, rb, w1, b1, w2, b2,
            xb, w1b, b1b, w2b, b2b, tok_epack, tok_w,
            counts, offsets, list, tok_pos, a_packed, y_packed, outp, GF);
        moe_mega<4><<<GF, 256, 0, stream>>>(x, rw, rb, w1, b1, w2, b2,
            xb, w1b, b1b, w2b, b2b, tok_epack, tok_w,
            counts, offsets, list, tok_pos, a_packed, y_packed, outp, GF);
    }
}

// Round 4
// 201.773 us; speedup vs baseline: 1.7714x; 1.7714x over previous
//
#include <hip/hip_runtime.h>

typedef unsigned int u32;
typedef unsigned short u16;
typedef unsigned long long u64;

#define NTOK 4096
#define DDIM 512
#define NEXP 8
#define HDIM 1024

typedef __attribute__((ext_vector_type(8))) __bf16 bf16x8;
typedef __attribute__((ext_vector_type(4))) float f32x4;

typedef const void __attribute__((address_space(1))) as1_cvoid;
typedef void __attribute__((address_space(3))) as3_void;

__device__ __forceinline__ float b2f(u16 u) {
    union { u32 i; float f; } v; v.i = ((u32)u) << 16; return v.f;
}
__device__ __forceinline__ u16 f2b(float f) {
    u32 x = __builtin_bit_cast(u32, f);
    x += 0x7fffu + ((x >> 16) & 1u);
    return (u16)(x >> 16);
}

// width-16 direct global->LDS. LDS dest is wave-uniform base + lane*16
// (linear); swizzle lives in the per-lane GLOBAL source address (rule 21).
__device__ __forceinline__ void gl16(const u16* g, u16* l) {
    __builtin_amdgcn_global_load_lds((as1_cvoid*)g, (as3_void*)l, 16, 0, 0);
}

// ---------------- K1: fused convert + zero-out + router ----------------
// REGRESSION NOTES:
//  - r1: per-token atomicAdd on counts[8] = 8192 serialized RMWs on one
//    cache line across 8 XCDs -> ~100us. Router writes only tok_epack/tok_w.
//  - r3: cooperative mega-kernel grid.sync() costs ~75us/sync on gfx950
//    (L2 writeback/invalidate across 8 non-coherent XCD L2s). Reverted.
#define CN0 ((size_t)NTOK * DDIM)                  // x        2,097,152
#define CN1 (CN0 + (size_t)NEXP * 2 * HDIM * DDIM) // fc1_w   +8,388,608
#define CN2 (CN1 + (size_t)NEXP * 2 * HDIM)        // fc1_b   +16,384
#define CN3 (CN2 + (size_t)NEXP * DDIM * HDIM)     // fc2_w   +4,194,304
#define CN4 (CN3 + (size_t)NEXP * DDIM)            // fc2_b   +4,096  => 14,700,544
#define CONV_BLOCKS 7178                            // exactly CN4/8/256
#define OUTZ_BLOCKS 1024                            // zero 2,097,152 f32 out
#define ROUTER_BLOCKS (NTOK / 4)

__global__ __launch_bounds__(256) void conv_router_kernel(
    const float* __restrict__ x,  const float* __restrict__ w1, const float* __restrict__ b1,
    const float* __restrict__ w2, const float* __restrict__ b2,
    u16* __restrict__ xb, u16* __restrict__ w1b, u16* __restrict__ b1b,
    u16* __restrict__ w2b, u16* __restrict__ b2b,
    const float* __restrict__ rw, const float* __restrict__ rb,
    u16* __restrict__ tok_epack, float* __restrict__ tok_w,
    float* __restrict__ out)
{
    const int tid = threadIdx.x;
    const int bid = (int)blockIdx.x;
    if (bid < CONV_BLOCKS) {
        const size_t i = ((size_t)bid * 256 + tid) * 8;
        if (i >= CN4) return;
        const float* src; u16* dst; size_t off;
        if (i < CN0)      { src = x;  dst = xb;  off = i; }
        else if (i < CN1) { src = w1; dst = w1b; off = i - CN0; }
        else if (i < CN2) { src = b1; dst = b1b; off = i - CN1; }
        else if (i < CN3) { src = w2; dst = w2b; off = i - CN2; }
        else              { src = b2; dst = b2b; off = i - CN3; }
        const float4 a = *(const float4*)(src + off);
        const float4 b = *(const float4*)(src + off + 4);
        union { u16 t[8]; uint4 v; } u;
        u.t[0] = f2b(a.x); u.t[1] = f2b(a.y); u.t[2] = f2b(a.z); u.t[3] = f2b(a.w);
        u.t[4] = f2b(b.x); u.t[5] = f2b(b.y); u.t[6] = f2b(b.z); u.t[7] = f2b(b.w);
        *(uint4*)(dst + off) = u.v;
        return;
    }
    if (bid < CONV_BLOCKS + OUTZ_BLOCKS) {
        // zero the f32 output (fc2 accumulates into it with atomics)
        const size_t i = ((size_t)(bid - CONV_BLOCKS) * 256 + tid) * 8;
        float* op = out + i;
        *(float4*)op       = float4{0.f, 0.f, 0.f, 0.f};
        *(float4*)(op + 4) = float4{0.f, 0.f, 0.f, 0.f};
        return;
    }

    // ---- router: one wave per token, f32 inputs ----
    const int lane = tid & 63;
    const int t = (bid - CONV_BLOCKS - OUTZ_BLOCKS) * 4 + (tid >> 6);

    const float4* p = (const float4*)(x + (size_t)t * DDIM + lane * 8);
    const float4 xa = p[0], xc = p[1];
    float xf[8] = { xa.x, xa.y, xa.z, xa.w, xc.x, xc.y, xc.z, xc.w };

    float acc[NEXP];
#pragma unroll
    for (int e = 0; e < NEXP; e++) {
        const float4* q = (const float4*)(rw + e * DDIM + lane * 8);
        const float4 wa = q[0], wb = q[1];
        acc[e] = xf[0] * wa.x + xf[1] * wa.y + xf[2] * wa.z + xf[3] * wa.w
               + xf[4] * wb.x + xf[5] * wb.y + xf[6] * wb.z + xf[7] * wb.w;
    }
#pragma unroll
    for (int off = 32; off > 0; off >>= 1) {
#pragma unroll
        for (int e = 0; e < NEXP; e++) acc[e] += __shfl_xor(acc[e], off, 64);
    }
    if (lane == 0) {
#pragma unroll
        for (int e = 0; e < NEXP; e++) acc[e] += rb[e];
        // top-2, lowest-index tie-break (matches lax.top_k)
        int e0 = 0;
#pragma unroll
        for (int e = 1; e < NEXP; e++) if (acc[e] > acc[e0]) e0 = e;
        int e1 = -1;
#pragma unroll
        for (int e = 0; e < NEXP; e++) {
            if (e == e0) continue;
            if (e1 < 0 || acc[e] > acc[e1]) e1 = e;
        }
        const float w1v = 1.f / (1.f + __expf(acc[e0] - acc[e1]));
        tok_epack[t] = (u16)((u32)e0 | ((u32)e1 << 8));
        tok_w[t * 2] = 1.f - w1v;
        tok_w[t * 2 + 1] = w1v;
    }
}

// ---------------- K2: build per-expert lists (single block, ballot compaction) ----------------
// 8 waves, one per expert; deterministic, zero atomics. Also emits the
// per-packed-row combine weight wlist[e][idx] so fc2 can fuse the combine.
__global__ __launch_bounds__(512) void build_lists_kernel(
    const u16* __restrict__ tok_epack, const float* __restrict__ tok_w,
    u32* __restrict__ counts, u32* __restrict__ offsets,
    u16* __restrict__ list, float* __restrict__ wlist)
{
    __shared__ u32 eLDS[NTOK / 2];   // packed token pairs
    __shared__ u32 cLDS[NEXP];
    const int tid = threadIdx.x;
    for (int i = tid; i < NTOK / 2; i += 512)
        eLDS[i] = ((const u32*)tok_epack)[i];
    __syncthreads();

    const int wave = tid >> 6, lane = tid & 63;
    const u64 ltmask = ((u64)1 << lane) - 1;   // lane<=63, no UB
    const u32 e = (u32)wave;                   // one expert per wave
    u32 r = 0;
    for (int c = 0; c < 64; c++) {
        const int t = c * 64 + lane;
        const u32 pair = eLDS[t >> 1];
        const u32 p = (pair >> ((t & 1) * 16)) & 0xFFFFu;
        const u32 e0 = p & 0xFFu, e1 = (p >> 8) & 0xFFu;
        const u64 m0 = __ballot(e0 == e);
        if (e0 == e) {
            const u32 idx = r + (u32)__popcll(m0 & ltmask);
            list[e * NTOK + idx] = (u16)t;
            wlist[e * NTOK + idx] = tok_w[t * 2];
        }
        r += (u32)__popcll(m0);
        const u64 m1 = __ballot(e1 == e);
        if (e1 == e) {
            const u32 idx = r + (u32)__popcll(m1 & ltmask);
            list[e * NTOK + idx] = (u16)t;
            wlist[e * NTOK + idx] = tok_w[t * 2 + 1];
        }
        r += (u32)__popcll(m1);
    }
    if (lane == 0) cLDS[e] = r;
    __syncthreads();
    if (tid == 0) {
        u32 o = 0;
        for (int i = 0; i < NEXP; i++) { counts[i] = cLDS[i]; offsets[i] = o; o += cLDS[i]; }
    }
}

// ---------------- K3: gathered fc1 + SwiGLU, 128x64 tile (round-2 verified body) ----------------
__global__ __launch_bounds__(256, 3) void fc1_swiglu_kernel(
    const u16* __restrict__ xb, const u16* __restrict__ w1b, const u16* __restrict__ b1b,
    const u32* __restrict__ counts, const u32* __restrict__ offsets,
    const u16* __restrict__ list, u16* __restrict__ a_packed)
{
    const int e = blockIdx.z;
    const int cnt = (int)counts[e];
    const int row0 = blockIdx.y * 128;
    if (row0 >= cnt) return;
    const int n0 = blockIdx.x * 64;

    __shared__ u16 As[128 * 64], B1s[64 * 64], B2s[64 * 64];

    const int tid = threadIdx.x;
    const int wave = tid >> 6, lane = tid & 63;
    const int mrow0 = (wave >> 1) * 64;
    const int ncol0 = (wave & 1) * 32;
    const int mm = lane & 15;
    const int qb = lane >> 4;
    const int msw = mm & 7;

    const u16 *srcA[4], *srcB1[2], *srcB2[2];
    u16 *dstA[4], *dstB1[2], *dstB2[2];
    const int lrow8 = lane >> 3;
    const int colOff = ((lane & 7) ^ lrow8) << 3;   // element offset (bf16)
#pragma unroll
    for (int j = 0; j < 4; j++) {               // A: 32 rows per wave
        int r = row0 + wave * 32 + j * 8 + lrow8;
        if (r >= cnt) r = cnt - 1;
        const int tok = min((int)list[e * NTOK + r], NTOK - 1);
        srcA[j] = xb + (size_t)tok * DDIM + colOff;
        dstA[j] = &As[(wave * 32 + j * 8) * 64];
    }
#pragma unroll
    for (int j = 0; j < 2; j++) {               // B1/B2: 16 rows per wave
        const int n = n0 + wave * 16 + j * 8 + lrow8;
        srcB1[j] = w1b + ((size_t)e * 2 * HDIM + n) * DDIM + colOff;
        srcB2[j] = w1b + ((size_t)e * 2 * HDIM + HDIM + n) * DDIM + colOff;
        dstB1[j] = &B1s[(wave * 16 + j * 8) * 64];
        dstB2[j] = &B2s[(wave * 16 + j * 8) * 64];
    }

    f32x4 acc1[4][2], acc2[4][2];
#pragma unroll
    for (int mt = 0; mt < 4; mt++)
#pragma unroll
        for (int nt = 0; nt < 2; nt++) {
            acc1[mt][nt] = f32x4{0, 0, 0, 0};
            acc2[mt][nt] = f32x4{0, 0, 0, 0};
        }

    for (int k0 = 0; k0 < DDIM; k0 += 64) {
        __syncthreads();
#pragma unroll
        for (int j = 0; j < 4; j++) gl16(srcA[j] + k0, dstA[j]);
#pragma unroll
        for (int j = 0; j < 2; j++) gl16(srcB1[j] + k0, dstB1[j]);
#pragma unroll
        for (int j = 0; j < 2; j++) gl16(srcB2[j] + k0, dstB2[j]);
        __syncthreads();   // compiler drains vmcnt(0) before s_barrier
#pragma unroll
        for (int kk = 0; kk < 2; kk++) {
            const int g = kk * 4 + qb;
            bf16x8 af[4];
#pragma unroll
            for (int mt = 0; mt < 4; mt++)
                af[mt] = *(const bf16x8*)(&As[(mrow0 + mt * 16 + mm) * 64 + ((g ^ msw) << 3)]);
#pragma unroll
            for (int nt = 0; nt < 2; nt++) {
                const bf16x8 b1f = *(const bf16x8*)(&B1s[(ncol0 + nt * 16 + mm) * 64 + ((g ^ msw) << 3)]);
                const bf16x8 b2f = *(const bf16x8*)(&B2s[(ncol0 + nt * 16 + mm) * 64 + ((g ^ msw) << 3)]);
#pragma unroll
                for (int mt = 0; mt < 4; mt++) {
                    acc1[mt][nt] = __builtin_amdgcn_mfma_f32_16x16x32_bf16(af[mt], b1f, acc1[mt][nt], 0, 0, 0);
                    acc2[mt][nt] = __builtin_amdgcn_mfma_f32_16x16x32_bf16(af[mt], b2f, acc2[mt][nt], 0, 0, 0);
                }
            }
        }
    }

    const u32 obase = offsets[e];
    const int rbv = qb * 4;
#pragma unroll
    for (int nt = 0; nt < 2; nt++) {
        const int n = n0 + ncol0 + nt * 16 + mm;
        const float bb1 = b2f(b1b[(size_t)e * 2 * HDIM + n]);
        const float bb2 = b2f(b1b[(size_t)e * 2 * HDIM + HDIM + n]);
#pragma unroll
        for (int mt = 0; mt < 4; mt++) {
#pragma unroll
            for (int r = 0; r < 4; r++) {
                const int gr = row0 + mrow0 + mt * 16 + rbv + r;
                if (gr < cnt) {
                    const float h1 = acc1[mt][nt][r] + bb1;
                    const float h2 = acc2[mt][nt][r] + bb2;
                    const float av = h1 / (1.f + __expf(-h1)) * h2;
                    a_packed[(size_t)(obase + (u32)gr) * HDIM + n] = f2b(av);
                }
            }
        }
    }
}

// ---------------- K4: fc2 + fused weighted combine (atomic f32 accumulate) ----------------
// Each (token, d) element receives exactly 2 atomic contributions (TOP_K=2),
// to distinct addresses -> throughput path through L2, no round-1-style
// serialization. out must be pre-zeroed (done in conv_router).
__global__ __launch_bounds__(256, 4) void fc2_kernel(
    const u16* __restrict__ a_packed, const u16* __restrict__ w2b, const u16* __restrict__ b2b,
    const u32* __restrict__ counts, const u32* __restrict__ offsets,
    const u16* __restrict__ list, const float* __restrict__ wlist,
    float* __restrict__ out)
{
    const int e = blockIdx.z;
    const int cnt = (int)counts[e];
    const int row0 = blockIdx.y * 128;
    if (row0 >= cnt) return;
    const int d0 = blockIdx.x * 64;
    const u32 obase = offsets[e];

    __shared__ u16 As[128 * 64], Bs[64 * 64];

    const int tid = threadIdx.x;
    const int wave = tid >> 6, lane = tid & 63;
    const int mrow0 = (wave >> 1) * 64;
    const int ncol0 = (wave & 1) * 32;
    const int mm = lane & 15;
    const int qb = lane >> 4;
    const int msw = mm & 7;

    const u16 *srcA[4], *srcB[2];
    u16 *dstA[4], *dstB[2];
    const int lrow8 = lane >> 3;
    const int colOff = ((lane & 7) ^ lrow8) << 3;
#pragma unroll
    for (int j = 0; j < 4; j++) {
        int r = row0 + wave * 32 + j * 8 + lrow8;
        if (r >= cnt) r = cnt - 1;
        srcA[j] = a_packed + (size_t)(obase + (u32)r) * HDIM + colOff;
        dstA[j] = &As[(wave * 32 + j * 8) * 64];
    }
#pragma unroll
    for (int j = 0; j < 2; j++) {
        const int d = d0 + wave * 16 + j * 8 + lrow8;
        srcB[j] = w2b + ((size_t)e * DDIM + d) * HDIM + colOff;
        dstB[j] = &Bs[(wave * 16 + j * 8) * 64];
    }

    f32x4 acc[4][2];
#pragma unroll
    for (int mt = 0; mt < 4; mt++)
#pragma unroll
        for (int nt = 0; nt < 2; nt++) acc[mt][nt] = f32x4{0, 0, 0, 0};

    for (int k0 = 0; k0 < HDIM; k0 += 64) {
        __syncthreads();
#pragma unroll
        for (int j = 0; j < 4; j++) gl16(srcA[j] + k0, dstA[j]);
#pragma unroll
        for (int j = 0; j < 2; j++) gl16(srcB[j] + k0, dstB[j]);
        __syncthreads();
#pragma unroll
        for (int kk = 0; kk < 2; kk++) {
            const int g = kk * 4 + qb;
            bf16x8 af[4];
#pragma unroll
            for (int mt = 0; mt < 4; mt++)
                af[mt] = *(const bf16x8*)(&As[(mrow0 + mt * 16 + mm) * 64 + ((g ^ msw) << 3)]);
#pragma unroll
            for (int nt = 0; nt < 2; nt++) {
                const bf16x8 bfv = *(const bf16x8*)(&Bs[(ncol0 + nt * 16 + mm) * 64 + ((g ^ msw) << 3)]);
#pragma unroll
                for (int mt = 0; mt < 4; mt++)
                    acc[mt][nt] = __builtin_amdgcn_mfma_f32_16x16x32_bf16(af[mt], bfv, acc[mt][nt], 0, 0, 0);
            }
        }
    }

    const int rbv = qb * 4;
    const float bb0 = b2f(b2b[(size_t)e * DDIM + d0 + ncol0 + mm]);
    const float bb1 = b2f(b2b[(size_t)e * DDIM + d0 + ncol0 + 16 + mm]);
#pragma unroll
    for (int mt = 0; mt < 4; mt++) {
#pragma unroll
        for (int r = 0; r < 4; r++) {
            const int gr = row0 + mrow0 + mt * 16 + rbv + r;
            if (gr < cnt) {
                const int t = (int)list[e * NTOK + gr];
                const float w = wlist[e * NTOK + gr];
                float* op = out + (size_t)t * DDIM + d0 + ncol0;
                atomicAdd(op + mm,      w * (acc[mt][0][r] + bb0));
                atomicAdd(op + 16 + mm, w * (acc[mt][1][r] + bb1));
            }
        }
    }
}

extern "C" void kernel_launch(void* const* d_in, const int* in_sizes, int n_in,
                              void* d_out, int out_size, void* d_ws, size_t ws_size,
                              hipStream_t stream)
{
    const float* x  = (const float*)d_in[0];
    const float* rw = (const float*)d_in[1];
    const float* rb = (const float*)d_in[2];
    const float* w1 = (const float*)d_in[3];
    const float* b1 = (const float*)d_in[4];
    const float* w2 = (const float*)d_in[5];
    const float* b2 = (const float*)d_in[6];
    float* outp = (float*)d_out;
    (void)in_sizes; (void)n_in; (void)out_size; (void)ws_size;

    char* ws = (char*)d_ws;
    size_t off = 0;
    auto take = [&](size_t bytes) -> char* {
        char* p = ws + off;
        off = (off + bytes + 255) & ~(size_t)255;
        return p;
    };
    u32* counts    = (u32*)take(NEXP * 4);
    u32* offsets   = (u32*)take(NEXP * 4);
    u16* list      = (u16*)take((size_t)NEXP * NTOK * 2);
    float* wlist   = (float*)take((size_t)NEXP * NTOK * 4);
    u16* tok_epack = (u16*)take((size_t)NTOK * 2);
    float* tok_w   = (float*)take((size_t)NTOK * 2 * 4);
    u16* a_packed  = (u16*)take((size_t)2 * NTOK * HDIM * 2);   // 16.8 MB
    u16* xb  = (u16*)take(CN0 * 2);                             // 4.2 MB
    u16* w1b = (u16*)take((size_t)NEXP * 2 * HDIM * DDIM * 2);  // 16.8 MB
    u16* b1b = (u16*)take((size_t)NEXP * 2 * HDIM * 2);
    u16* w2b = (u16*)take((size_t)NEXP * DDIM * HDIM * 2);      // 8.4 MB
    u16* b2b = (u16*)take((size_t)NEXP * DDIM * 2);

    conv_router_kernel<<<CONV_BLOCKS + OUTZ_BLOCKS + ROUTER_BLOCKS, 256, 0, stream>>>(
        x, w1, b1, w2, b2, xb, w1b, b1b, w2b, b2b, rw, rb,
        tok_epack, tok_w, outp);

    build_lists_kernel<<<1, 512, 0, stream>>>(tok_epack, tok_w, counts, offsets, list, wlist);

    const dim3 g1(HDIM / 64, NTOK / 128, NEXP);
    fc1_swiglu_kernel<<<g1, 256, 0, stream>>>(xb, w1b, b1b, counts, offsets, list, a_packed);

    const dim3 g2(DDIM / 64, NTOK / 128, NEXP);
    fc2_kernel<<<g2, 256, 0, stream>>>(a_packed, w2b, b2b, counts, offsets, list, wlist, outp);
}

// Round 5
// 182.276 us; speedup vs baseline: 1.9609x; 1.1070x over previous
//
#include <hip/hip_runtime.h>

typedef unsigned int u32;
typedef unsigned short u16;
typedef unsigned long long u64;

#define NTOK 4096
#define DDIM 512
#define NEXP 8
#define HDIM 1024

typedef __attribute__((ext_vector_type(8))) __bf16 bf16x8;
typedef __attribute__((ext_vector_type(4))) float f32x4;

typedef const void __attribute__((address_space(1))) as1_cvoid;
typedef void __attribute__((address_space(3))) as3_void;

__device__ __forceinline__ float b2f(u16 u) {
    union { u32 i; float f; } v; v.i = ((u32)u) << 16; return v.f;
}
__device__ __forceinline__ u16 f2b(float f) {
    u32 x = __builtin_bit_cast(u32, f);
    x += 0x7fffu + ((x >> 16) & 1u);
    return (u16)(x >> 16);
}

// width-16 direct global->LDS. LDS dest is wave-uniform base + lane*16
// (linear); swizzle lives in the per-lane GLOBAL source address (rule 21).
__device__ __forceinline__ void gl16(const u16* g, u16* l) {
    __builtin_amdgcn_global_load_lds((as1_cvoid*)g, (as3_void*)l, 16, 0, 0);
}

// REGRESSION LEDGER (settled, do not retry):
//  r1: per-token atomicAdd on counts[8] -> 8192 serialized RMWs on one line
//      across 8 XCDs, ~100us. Lists must be built without hot-line atomics.
//  r3: cooperative grid.sync() ~75us/sync on gfx950 (XCD L2 flush). Dead end.
//  r4: fusing combine into fc2 via scattered f32 atomicAdd (+16us net):
//      4.2M uncoalesced 4B RMWs beat the cost of a whole combine pass.
//      Epilogues stay bulk coalesced; scatter lives in its own pass.

#define CN0 ((size_t)NTOK * DDIM)                  // x        2,097,152
#define CN1 (CN0 + (size_t)NEXP * 2 * HDIM * DDIM) // fc1_w   +8,388,608
#define CN2 (CN1 + (size_t)NEXP * 2 * HDIM)        // fc1_b   +16,384
#define CN3 (CN2 + (size_t)NEXP * DDIM * HDIM)     // fc2_w   +4,194,304
#define CN4 (CN3 + (size_t)NEXP * DDIM)            // fc2_b   +4,096  => 14,700,544
#define CONV_BLOCKS 7178                            // exactly CN4/8/256

// ---------------- K1: router (one wave per token) ----------------
__global__ __launch_bounds__(256) void router_kernel(
    const float* __restrict__ x, const float* __restrict__ rw, const float* __restrict__ rb,
    u16* __restrict__ tok_epack, float* __restrict__ tok_w)
{
    const int tid = threadIdx.x;
    const int lane = tid & 63;
    const int t = (int)blockIdx.x * 4 + (tid >> 6);

    const float4* p = (const float4*)(x + (size_t)t * DDIM + lane * 8);
    const float4 xa = p[0], xc = p[1];
    float xf[8] = { xa.x, xa.y, xa.z, xa.w, xc.x, xc.y, xc.z, xc.w };

    float acc[NEXP];
#pragma unroll
    for (int e = 0; e < NEXP; e++) {
        const float4* q = (const float4*)(rw + e * DDIM + lane * 8);
        const float4 wa = q[0], wb = q[1];
        acc[e] = xf[0] * wa.x + xf[1] * wa.y + xf[2] * wa.z + xf[3] * wa.w
               + xf[4] * wb.x + xf[5] * wb.y + xf[6] * wb.z + xf[7] * wb.w;
    }
#pragma unroll
    for (int off = 32; off > 0; off >>= 1) {
#pragma unroll
        for (int e = 0; e < NEXP; e++) acc[e] += __shfl_xor(acc[e], off, 64);
    }
    if (lane == 0) {
#pragma unroll
        for (int e = 0; e < NEXP; e++) acc[e] += rb[e];
        // top-2, lowest-index tie-break (matches lax.top_k)
        int e0 = 0;
#pragma unroll
        for (int e = 1; e < NEXP; e++) if (acc[e] > acc[e0]) e0 = e;
        int e1 = -1;
#pragma unroll
        for (int e = 0; e < NEXP; e++) {
            if (e == e0) continue;
            if (e1 < 0 || acc[e] > acc[e1]) e1 = e;
        }
        const float w1v = 1.f / (1.f + __expf(acc[e0] - acc[e1]));
        tok_epack[t] = (u16)((u32)e0 | ((u32)e1 << 8));
        tok_w[t * 2] = 1.f - w1v;
        tok_w[t * 2 + 1] = w1v;
    }
}

// ---------------- K2: convert + build lists (block 0) ----------------
// build_lists depends only on router output, so it runs as block 0 here and
// hides under the 7178 convert blocks (~20us) instead of being an exposed
// serial launch. 256-thread ballot-compaction variant verified in r3.
__global__ __launch_bounds__(256) void conv_build_kernel(
    const float* __restrict__ x,  const float* __restrict__ w1, const float* __restrict__ b1,
    const float* __restrict__ w2, const float* __restrict__ b2,
    u16* __restrict__ xb, u16* __restrict__ w1b, u16* __restrict__ b1b,
    u16* __restrict__ w2b, u16* __restrict__ b2b,
    const u16* __restrict__ tok_epack,
    u32* __restrict__ counts, u32* __restrict__ offsets,
    u16* __restrict__ list, u32* __restrict__ tok_pos)
{
    const int tid = threadIdx.x;
    const int bid = (int)blockIdx.x;

    if (bid == 0) {
        __shared__ u32 eLDS[NTOK / 2 + NEXP];
        u32* cLDS = eLDS + NTOK / 2;
        for (int i = tid; i < NTOK / 2; i += 256) eLDS[i] = ((const u32*)tok_epack)[i];
        __syncthreads();
        const int wave = tid >> 6, lane = tid & 63;
        const u64 ltmask = ((u64)1 << lane) - 1;
#pragma unroll
        for (int pass = 0; pass < 2; pass++) {
            const u32 e = (u32)(wave + pass * 4);
            u32 r = 0;
            for (int c = 0; c < 64; c++) {
                const int t = c * 64 + lane;
                const u32 pair = eLDS[t >> 1];
                const u32 p = (pair >> ((t & 1) * 16)) & 0xFFFFu;
                const u32 e0 = p & 0xFFu, e1v = (p >> 8) & 0xFFu;
                const u64 m0 = __ballot(e0 == e);
                if (e0 == e) {
                    const u32 idx = r + (u32)__popcll(m0 & ltmask);
                    list[e * NTOK + idx] = (u16)t;
                    tok_pos[t * 2] = idx;
                }
                r += (u32)__popcll(m0);
                const u64 m1 = __ballot(e1v == e);
                if (e1v == e) {
                    const u32 idx = r + (u32)__popcll(m1 & ltmask);
                    list[e * NTOK + idx] = (u16)t;
                    tok_pos[t * 2 + 1] = idx;
                }
                r += (u32)__popcll(m1);
            }
            if (lane == 0) cLDS[e] = r;
        }
        __syncthreads();
        if (tid == 0) {
            u32 o = 0;
            for (int i = 0; i < NEXP; i++) { counts[i] = cLDS[i]; offsets[i] = o; o += cLDS[i]; }
        }
        return;
    }

    const size_t i = ((size_t)(bid - 1) * 256 + tid) * 8;
    if (i >= CN4) return;
    const float* src; u16* dst; size_t off;
    if (i < CN0)      { src = x;  dst = xb;  off = i; }
    else if (i < CN1) { src = w1; dst = w1b; off = i - CN0; }
    else if (i < CN2) { src = b1; dst = b1b; off = i - CN1; }
    else if (i < CN3) { src = w2; dst = w2b; off = i - CN2; }
    else              { src = b2; dst = b2b; off = i - CN3; }
    const float4 a = *(const float4*)(src + off);
    const float4 b = *(const float4*)(src + off + 4);
    union { u16 t[8]; uint4 v; } u;
    u.t[0] = f2b(a.x); u.t[1] = f2b(a.y); u.t[2] = f2b(a.z); u.t[3] = f2b(a.w);
    u.t[4] = f2b(b.x); u.t[5] = f2b(b.y); u.t[6] = f2b(b.z); u.t[7] = f2b(b.w);
    *(uint4*)(dst + off) = u.v;
}

// ---------------- K3: gathered fc1 + SwiGLU, 128x64 tile (r2-verified body) ----------------
__global__ __launch_bounds__(256, 3) void fc1_swiglu_kernel(
    const u16* __restrict__ xb, const u16* __restrict__ w1b, const u16* __restrict__ b1b,
    const u32* __restrict__ counts, const u32* __restrict__ offsets,
    const u16* __restrict__ list, u16* __restrict__ a_packed)
{
    const int e = blockIdx.z;
    const int cnt = (int)counts[e];
    const int row0 = blockIdx.y * 128;
    if (row0 >= cnt) return;
    const int n0 = blockIdx.x * 64;

    __shared__ u16 As[128 * 64], B1s[64 * 64], B2s[64 * 64];

    const int tid = threadIdx.x;
    const int wave = tid >> 6, lane = tid & 63;
    const int mrow0 = (wave >> 1) * 64;
    const int ncol0 = (wave & 1) * 32;
    const int mm = lane & 15;
    const int qb = lane >> 4;
    const int msw = mm & 7;

    const u16 *srcA[4], *srcB1[2], *srcB2[2];
    u16 *dstA[4], *dstB1[2], *dstB2[2];
    const int lrow8 = lane >> 3;
    const int colOff = ((lane & 7) ^ lrow8) << 3;   // element offset (bf16)
#pragma unroll
    for (int j = 0; j < 4; j++) {               // A: 32 rows per wave
        int r = row0 + wave * 32 + j * 8 + lrow8;
        if (r >= cnt) r = cnt - 1;
        const int tok = min((int)list[e * NTOK + r], NTOK - 1);
        srcA[j] = xb + (size_t)tok * DDIM + colOff;
        dstA[j] = &As[(wave * 32 + j * 8) * 64];
    }
#pragma unroll
    for (int j = 0; j < 2; j++) {               // B1/B2: 16 rows per wave
        const int n = n0 + wave * 16 + j * 8 + lrow8;
        srcB1[j] = w1b + ((size_t)e * 2 * HDIM + n) * DDIM + colOff;
        srcB2[j] = w1b + ((size_t)e * 2 * HDIM + HDIM + n) * DDIM + colOff;
        dstB1[j] = &B1s[(wave * 16 + j * 8) * 64];
        dstB2[j] = &B2s[(wave * 16 + j * 8) * 64];
    }

    f32x4 acc1[4][2], acc2[4][2];
#pragma unroll
    for (int mt = 0; mt < 4; mt++)
#pragma unroll
        for (int nt = 0; nt < 2; nt++) {
            acc1[mt][nt] = f32x4{0, 0, 0, 0};
            acc2[mt][nt] = f32x4{0, 0, 0, 0};
        }

    for (int k0 = 0; k0 < DDIM; k0 += 64) {
        __syncthreads();
#pragma unroll
        for (int j = 0; j < 4; j++) gl16(srcA[j] + k0, dstA[j]);
#pragma unroll
        for (int j = 0; j < 2; j++) gl16(srcB1[j] + k0, dstB1[j]);
#pragma unroll
        for (int j = 0; j < 2; j++) gl16(srcB2[j] + k0, dstB2[j]);
        __syncthreads();   // drains vmcnt(0) before s_barrier
#pragma unroll
        for (int kk = 0; kk < 2; kk++) {
            const int g = kk * 4 + qb;
            bf16x8 af[4];
#pragma unroll
            for (int mt = 0; mt < 4; mt++)
                af[mt] = *(const bf16x8*)(&As[(mrow0 + mt * 16 + mm) * 64 + ((g ^ msw) << 3)]);
#pragma unroll
            for (int nt = 0; nt < 2; nt++) {
                const bf16x8 b1f = *(const bf16x8*)(&B1s[(ncol0 + nt * 16 + mm) * 64 + ((g ^ msw) << 3)]);
                const bf16x8 b2f = *(const bf16x8*)(&B2s[(ncol0 + nt * 16 + mm) * 64 + ((g ^ msw) << 3)]);
#pragma unroll
                for (int mt = 0; mt < 4; mt++) {
                    acc1[mt][nt] = __builtin_amdgcn_mfma_f32_16x16x32_bf16(af[mt], b1f, acc1[mt][nt], 0, 0, 0);
                    acc2[mt][nt] = __builtin_amdgcn_mfma_f32_16x16x32_bf16(af[mt], b2f, acc2[mt][nt], 0, 0, 0);
                }
            }
        }
    }

    const u32 obase = offsets[e];
    const int rbv = qb * 4;
#pragma unroll
    for (int nt = 0; nt < 2; nt++) {
        const int n = n0 + ncol0 + nt * 16 + mm;
        const float bb1 = b2f(b1b[(size_t)e * 2 * HDIM + n]);
        const float bb2 = b2f(b1b[(size_t)e * 2 * HDIM + HDIM + n]);
#pragma unroll
        for (int mt = 0; mt < 4; mt++) {
#pragma unroll
            for (int r = 0; r < 4; r++) {
                const int gr = row0 + mrow0 + mt * 16 + rbv + r;
                if (gr < cnt) {
                    const float h1 = acc1[mt][nt][r] + bb1;
                    const float h2 = acc2[mt][nt][r] + bb2;
                    const float av = h1 / (1.f + __expf(-h1)) * h2;
                    a_packed[(size_t)(obase + (u32)gr) * HDIM + n] = f2b(av);
                }
            }
        }
    }
}

// ---------------- K4: fc2, 128x64 tile, double-buffered 2-phase prefetch ----------------
// fc2 has the worst TLP (~2 active blocks/CU) so its exposed stage stall is
// least hidden by other waves; stage k+1 into buf^1 before computing k.
// LDS 48KB -> still 3 blocks/CU.
__global__ __launch_bounds__(256, 3) void fc2_kernel(
    const u16* __restrict__ a_packed, const u16* __restrict__ w2b, const u16* __restrict__ b2b,
    const u32* __restrict__ counts, const u32* __restrict__ offsets,
    u16* __restrict__ y_packed)
{
    const int e = blockIdx.z;
    const int cnt = (int)counts[e];
    const int row0 = blockIdx.y * 128;
    if (row0 >= cnt) return;
    const int d0 = blockIdx.x * 64;
    const u32 obase = offsets[e];

    __shared__ u16 As[2 * 128 * 64], Bs[2 * 64 * 64];   // 32KB + 16KB

    const int tid = threadIdx.x;
    const int wave = tid >> 6, lane = tid & 63;
    const int mrow0 = (wave >> 1) * 64;
    const int ncol0 = (wave & 1) * 32;
    const int mm = lane & 15;
    const int qb = lane >> 4;
    const int msw = mm & 7;

    const u16 *srcA[4], *srcB[2];
    int dA[4], dB[2];
    const int lrow8 = lane >> 3;
    const int colOff = ((lane & 7) ^ lrow8) << 3;
#pragma unroll
    for (int j = 0; j < 4; j++) {
        int r = row0 + wave * 32 + j * 8 + lrow8;
        if (r >= cnt) r = cnt - 1;
        srcA[j] = a_packed + (size_t)(obase + (u32)r) * HDIM + colOff;
        dA[j] = (wave * 32 + j * 8) * 64;
    }
#pragma unroll
    for (int j = 0; j < 2; j++) {
        const int d = d0 + wave * 16 + j * 8 + lrow8;
        srcB[j] = w2b + ((size_t)e * DDIM + d) * HDIM + colOff;
        dB[j] = (wave * 16 + j * 8) * 64;
    }

    f32x4 acc[4][2];
#pragma unroll
    for (int mt = 0; mt < 4; mt++)
#pragma unroll
        for (int nt = 0; nt < 2; nt++) acc[mt][nt] = f32x4{0, 0, 0, 0};

    // prologue: stage k0=0 into buffer 0
#pragma unroll
    for (int j = 0; j < 4; j++) gl16(srcA[j], As + dA[j]);
#pragma unroll
    for (int j = 0; j < 2; j++) gl16(srcB[j], Bs + dB[j]);
    __syncthreads();   // vmcnt(0) drain

    int cur = 0;
    for (int k0 = 0; k0 < HDIM; k0 += 64) {
        const int nxt = cur ^ 1;
        if (k0 + 64 < HDIM) {
#pragma unroll
            for (int j = 0; j < 4; j++) gl16(srcA[j] + k0 + 64, As + nxt * 8192 + dA[j]);
#pragma unroll
            for (int j = 0; j < 2; j++) gl16(srcB[j] + k0 + 64, Bs + nxt * 4096 + dB[j]);
        }
        const u16* Ab = As + cur * 8192;
        const u16* Bb = Bs + cur * 4096;
#pragma unroll
        for (int kk = 0; kk < 2; kk++) {
            const int g = kk * 4 + qb;
            bf16x8 af[4];
#pragma unroll
            for (int mt = 0; mt < 4; mt++)
                af[mt] = *(const bf16x8*)(&Ab[(mrow0 + mt * 16 + mm) * 64 + ((g ^ msw) << 3)]);
#pragma unroll
            for (int nt = 0; nt < 2; nt++) {
                const bf16x8 bfv = *(const bf16x8*)(&Bb[(ncol0 + nt * 16 + mm) * 64 + ((g ^ msw) << 3)]);
#pragma unroll
                for (int mt = 0; mt < 4; mt++)
                    acc[mt][nt] = __builtin_amdgcn_mfma_f32_16x16x32_bf16(af[mt], bfv, acc[mt][nt], 0, 0, 0);
            }
        }
        __syncthreads();   // drains vmcnt(0): next-tile stage complete
        cur = nxt;
    }

    const int rbv = qb * 4;
#pragma unroll
    for (int nt = 0; nt < 2; nt++) {
        const int n = d0 + ncol0 + nt * 16 + mm;
        const float bb = b2f(b2b[(size_t)e * DDIM + n]);
#pragma unroll
        for (int mt = 0; mt < 4; mt++) {
#pragma unroll
            for (int r = 0; r < 4; r++) {
                const int gr = row0 + mrow0 + mt * 16 + rbv + r;
                if (gr < cnt) {
                    y_packed[(size_t)(obase + (u32)gr) * DDIM + n] = f2b(acc[mt][nt][r] + bb);
                }
            }
        }
    }
}

// ---------------- K5: weighted combine (vectorized, 4 tokens/block) ----------------
__global__ __launch_bounds__(256) void combine_kernel(
    const u16* __restrict__ y_packed, const u32* __restrict__ offsets,
    const u16* __restrict__ tok_epack, const u32* __restrict__ tok_pos,
    const float* __restrict__ tok_w, float* __restrict__ out)
{
    const int tid = threadIdx.x;
    const int lane = tid & 63;
    const int t = (int)blockIdx.x * 4 + (tid >> 6);
    const u32 pk = (u32)tok_epack[t];
    const u32 e0 = pk & 7u, e1 = (pk >> 8) & 7u;
    const u32 p0 = min(offsets[e0] + tok_pos[t * 2],     (u32)(2 * NTOK - 1));
    const u32 p1 = min(offsets[e1] + tok_pos[t * 2 + 1], (u32)(2 * NTOK - 1));
    const float w0 = tok_w[t * 2], w1 = tok_w[t * 2 + 1];

    const uint4 va = *(const uint4*)(y_packed + (size_t)p0 * DDIM + lane * 8);
    const uint4 vb = *(const uint4*)(y_packed + (size_t)p1 * DDIM + lane * 8);
    const u16* ap = (const u16*)&va;
    const u16* bp = (const u16*)&vb;
    float r[8];
#pragma unroll
    for (int j = 0; j < 8; j++) r[j] = w0 * b2f(ap[j]) + w1 * b2f(bp[j]);

    float* op = out + (size_t)t * DDIM + lane * 8;
    *(float4*)op       = float4{r[0], r[1], r[2], r[3]};
    *(float4*)(op + 4) = float4{r[4], r[5], r[6], r[7]};
}

extern "C" void kernel_launch(void* const* d_in, const int* in_sizes, int n_in,
                              void* d_out, int out_size, void* d_ws, size_t ws_size,
                              hipStream_t stream)
{
    const float* x  = (const float*)d_in[0];
    const float* rw = (const float*)d_in[1];
    const float* rb = (const float*)d_in[2];
    const float* w1 = (const float*)d_in[3];
    const float* b1 = (const float*)d_in[4];
    const float* w2 = (const float*)d_in[5];
    const float* b2 = (const float*)d_in[6];
    float* outp = (float*)d_out;
    (void)in_sizes; (void)n_in; (void)out_size; (void)ws_size;

    char* ws = (char*)d_ws;
    size_t off = 0;
    auto take = [&](size_t bytes) -> char* {
        char* p = ws + off;
        off = (off + bytes + 255) & ~(size_t)255;
        return p;
    };
    u32* counts    = (u32*)take(NEXP * 4);
    u32* offsets   = (u32*)take(NEXP * 4);
    u16* list      = (u16*)take((size_t)NEXP * NTOK * 2);
    u16* tok_epack = (u16*)take((size_t)NTOK * 2);
    u32* tok_pos   = (u32*)take((size_t)NTOK * 2 * 4);
    float* tok_w   = (float*)take((size_t)NTOK * 2 * 4);
    u16* a_packed  = (u16*)take((size_t)2 * NTOK * HDIM * 2);   // 16.8 MB
    u16* y_packed  = (u16*)take((size_t)2 * NTOK * DDIM * 2);   // 8.4 MB
    u16* xb  = (u16*)take(CN0 * 2);                             // 4.2 MB
    u16* w1b = (u16*)take((size_t)NEXP * 2 * HDIM * DDIM * 2);  // 16.8 MB
    u16* b1b = (u16*)take((size_t)NEXP * 2 * HDIM * 2);
    u16* w2b = (u16*)take((size_t)NEXP * DDIM * HDIM * 2);      // 8.4 MB
    u16* b2b = (u16*)take((size_t)NEXP * DDIM * 2);

    router_kernel<<<NTOK / 4, 256, 0, stream>>>(x, rw, rb, tok_epack, tok_w);

    conv_build_kernel<<<CONV_BLOCKS + 1, 256, 0, stream>>>(
        x, w1, b1, w2, b2, xb, w1b, b1b, w2b, b2b,
        tok_epack, counts, offsets, list, tok_pos);

    const dim3 g1(HDIM / 64, NTOK / 128, NEXP);
    fc1_swiglu_kernel<<<g1, 256, 0, stream>>>(xb, w1b, b1b, counts, offsets, list, a_packed);

    const dim3 g2(DDIM / 64, NTOK / 128, NEXP);
    fc2_kernel<<<g2, 256, 0, stream>>>(a_packed, w2b, b2b, counts, offsets, y_packed);

    combine_kernel<<<NTOK / 4, 256, 0, stream>>>(y_packed, offsets, tok_epack, tok_pos, tok_w, outp);
}